// Round 7
// baseline (53.765 us; speedup 1.0000x reference)
//
#include <hip/hip_runtime.h>
#include <cstdint>

#define BDIM 4
#define NDIM 2048
#define FDIM 64
#define CDIM 64
#define LDIM 3
#define KTOT (NDIM * LDIM)   /* 6144 */
#define BK 128
#define NSTEP (KTOT / BK)    /* 48 */
#define KB (KTOT / 32)       /* 192 */

typedef __attribute__((ext_vector_type(4))) float f32x4;
typedef __attribute__((ext_vector_type(8))) short s16x8;
typedef __attribute__((ext_vector_type(4))) unsigned int u32x4;

__device__ __forceinline__ unsigned short f2bf(float x) {
  union { float f; uint32_t u; } v; v.f = x;
  uint32_t r = v.u + 0x7FFFu + ((v.u >> 16) & 1u);
  return (unsigned short)(r >> 16);
}

__device__ __forceinline__ uint32_t cvtpk(float lo, float hi) {
  uint32_t r;
  asm("v_cvt_pk_bf16_f32 %0, %1, %2" : "=v"(r) : "v"(lo), "v"(hi));
  return r;
}

// ---------------------------------------------------------------------------
// K1: S[b,i,c] = sum_f h0[c,f] V[b,i,f]   (fp32, ws)
//     Ut3[b][kb][cw][g][q][e] = U[b][c=cw*16+q][k=kb*32+g*8+e]  (bf16, ws)
//     where U[b][c][k=j*3+l] = sum_f h_{1+l}[c,f] V[b,j,f].
// Layout: k2's per-(kb,cw) wave B-load is 1 KB contiguous (lane*16B).
// MFMA 16x16x32 lane maps (verified R1-R6, absmax 0.5):
//   A: row=l&15, k=(l>>4)*8+e ; B: col=l&15, same k ; D: col=l&15, row=(l>>4)*4+rr
// ---------------------------------------------------------------------------
__global__ __launch_bounds__(64) void k1_precompute(
    const float* __restrict__ V, const float* __restrict__ hw,
    float* __restrict__ S, unsigned short* __restrict__ Ut3) {
  const int j0 = blockIdx.x * 16;
  const int le = blockIdx.y;
  const int b  = blockIdx.z;
  const int lane = threadIdx.x;
  const int q = lane & 15, g = lane >> 4;

  const float* vrow = V + ((size_t)(b * NDIM + j0 + q)) * FDIM + g * 8;
  f32x4 va0 = *(const f32x4*)(vrow);
  f32x4 va1 = *(const f32x4*)(vrow + 4);
  f32x4 va2 = *(const f32x4*)(vrow + 32);
  f32x4 va3 = *(const f32x4*)(vrow + 36);
  s16x8 a0, a1;
#pragma unroll
  for (int e = 0; e < 4; ++e) {
    a0[e]     = (short)f2bf(va0[e]);
    a0[e + 4] = (short)f2bf(va1[e]);
    a1[e]     = (short)f2bf(va2[e]);
    a1[e + 4] = (short)f2bf(va3[e]);
  }

  const float* hbase = hw + (size_t)le * CDIM * FDIM;
#pragma unroll
  for (int ct = 0; ct < 4; ++ct) {
    const float* hrow = hbase + (size_t)(ct * 16 + q) * FDIM + g * 8;
    f32x4 hb0 = *(const f32x4*)(hrow);
    f32x4 hb1 = *(const f32x4*)(hrow + 4);
    f32x4 hb2 = *(const f32x4*)(hrow + 32);
    f32x4 hb3 = *(const f32x4*)(hrow + 36);
    s16x8 b0, b1;
#pragma unroll
    for (int e = 0; e < 4; ++e) {
      b0[e]     = (short)f2bf(hb0[e]);
      b0[e + 4] = (short)f2bf(hb1[e]);
      b1[e]     = (short)f2bf(hb2[e]);
      b1[e + 4] = (short)f2bf(hb3[e]);
    }
    f32x4 acc = {0.f, 0.f, 0.f, 0.f};
    acc = __builtin_amdgcn_mfma_f32_16x16x32_bf16(a0, b0, acc, 0, 0, 0);
    acc = __builtin_amdgcn_mfma_f32_16x16x32_bf16(a1, b1, acc, 0, 0, 0);
    if (le == 0) {
#pragma unroll
      for (int rr = 0; rr < 4; ++rr) {
        int j = j0 + g * 4 + rr;
        S[((size_t)b * NDIM + j) * CDIM + ct * 16 + q] = acc[rr];
      }
    } else {
#pragma unroll
      for (int rr = 0; rr < 4; ++rr) {
        int j = j0 + g * 4 + rr;
        int k = j * 3 + (le - 1);
        int kb = k >> 5, gg = (k >> 3) & 3, ee = k & 7;
        size_t off = ((size_t)b * KB + kb) * 2048 + (size_t)ct * 512 +
                     (size_t)gg * 128 + (size_t)q * 8 + ee;
        Ut3[off] = f2bf(acc[rr]);
      }
    }
  }
}

// ---------------------------------------------------------------------------
// K2: out[b, i0..i0+31, :] = relu(S + A[b,i0:i0+32,:] @ U[b])
// M=32, BK=128/step, 48 steps, grid 256 = 1 block/CU, 4 waves.
// Wave (wr,wc)=(w>>1,w&1): rows wr*16..+15, cols wc*32..+31.
// B:A L2 traffic 1:1 (vs 2:1 at M=16); wr-paired waves load identical B
// slices barrier-synced -> L1 dedups -> L2 demand ~37 B/cy < 56 avail.
// A: GLL ring 4 x 16KB (64 KB static LDS), ahead-2, 512B row-granules,
//    source granule XOR-preswizzled by row&7 (involution; read applies same).
// Region order [B(s+1)x8, sched_barrier, GLL A(s+2)x4] -> vmcnt(16)
//    (newer-than-B(s) = A(s+1)4+B(s+1)8+A(s+2)4 = 16). NEVER vmcnt(0) in loop.
// ---------------------------------------------------------------------------
__global__ __launch_bounds__(256) void k2_main(
    const float* __restrict__ A, const unsigned short* __restrict__ Ut3,
    const float* __restrict__ S, float* __restrict__ out) {
  __shared__ float Abuf[4][4096];  // 4 slots x 32 rows x 128 floats = 64 KB

  const int bid = blockIdx.x;
  const int swz = (bid & 7) * 32 + (bid >> 3);  // XCD-chunked, 256 % 8 == 0
  const int b   = swz >> 6;
  const int i0  = (swz & 63) * 32;
  const int tid = threadIdx.x;
  const int lane = tid & 63, w = tid >> 6;
  const int q = lane & 15, g = lane >> 4, q7 = q & 7;
  const int wr = w >> 1, wc = w & 1;

  // A sources: wave w stages rows 8w..8w+7; GLL t covers rows 8w+2t, 8w+2t+1
  // (each row-chunk 512B); src granule (l&31) ^ (row&7) pre-swizzled.
  const int arowA = 8 * w + ((lane >> 5) & 1);  // base row parity for this lane
  // per-GLL t: row = 8w + 2t + (lane>>5)
  const float* agp[4];
#pragma unroll
  for (int t = 0; t < 4; ++t) {
    int r = 8 * w + 2 * t + (lane >> 5);
    int gran = (lane & 31) ^ (r & 7);
    agp[t] = A + ((size_t)(b * NDIM + i0 + r)) * KTOT + gran * 4;
  }
  (void)arowA;

  // B source: wave loads cw in {2wc, 2wc+1}, per step 4 kb x 2 cw x 1KB
  const unsigned short* bgp =
      Ut3 + (size_t)b * KB * 2048 + (size_t)(wc * 2) * 512 + (size_t)lane * 8;

  // LDS dest: wave region = 8 rows x 128 floats = 1024 floats; lane-linear
  float* ldsw = &Abuf[0][0] + w * 1024 + lane * 4;

#define GLL4(slot)                                                            \
  do {                                                                        \
    __builtin_amdgcn_global_load_lds(                                         \
        (__attribute__((address_space(1))) void*)(agp[0]),                    \
        (__attribute__((address_space(3))) void*)(ldsw + (slot) * 4096), 16, 0, 0); \
    __builtin_amdgcn_global_load_lds(                                         \
        (__attribute__((address_space(1))) void*)(agp[1]),                    \
        (__attribute__((address_space(3))) void*)(ldsw + (slot) * 4096 + 256), 16, 0, 0); \
    __builtin_amdgcn_global_load_lds(                                         \
        (__attribute__((address_space(1))) void*)(agp[2]),                    \
        (__attribute__((address_space(3))) void*)(ldsw + (slot) * 4096 + 512), 16, 0, 0); \
    __builtin_amdgcn_global_load_lds(                                         \
        (__attribute__((address_space(1))) void*)(agp[3]),                    \
        (__attribute__((address_space(3))) void*)(ldsw + (slot) * 4096 + 768), 16, 0, 0); \
  } while (0)

#define AADV(cond)                                                            \
  do { if (cond) { agp[0] += BK; agp[1] += BK; agp[2] += BK; agp[3] += BK; } } while (0)

#define LDB(BW)                                                               \
  do {                                                                        \
    _Pragma("unroll")                                                         \
    for (int t = 0; t < 4; ++t) {                                             \
      BW[t * 2 + 0] = *(const s16x8*)(bgp + (size_t)t * 2048);                \
      BW[t * 2 + 1] = *(const s16x8*)(bgp + (size_t)t * 2048 + 512);          \
    }                                                                         \
  } while (0)

  f32x4 acc0 = {0.f, 0.f, 0.f, 0.f}, acc1 = {0.f, 0.f, 0.f, 0.f};
  s16x8 bA[8], bB[8];

  // prologue: [A(0)x4, B(0)x8, A(1)x4] -> matches steady-state history
  GLL4(0); AADV(true);
  LDB(bA); bgp += 4 * 2048;
  GLL4(1); AADV(true);

  int s = 0;
  // region s: [B(s+1)x8, sched_barrier, A(s+2)x4, vmcnt(16), barrier, compute]
  // GLL(s+2) overwrites slot (s+2)&3 = slot of s-2; all waves finished its
  // reads before barrier s-1 => race-free with one barrier per step.
#define K2STEP(BW, BR)                                                        \
  do {                                                                        \
    LDB(BW);                                                                  \
    if (s + 2 < NSTEP) bgp += 4 * 2048; /* else re-read last (unused) */      \
    __builtin_amdgcn_sched_barrier(0);                                        \
    GLL4((s + 2) & 3);                                                        \
    AADV(s + 3 < NSTEP); /* else re-read last step's addrs into dead slot */  \
    asm volatile("s_waitcnt vmcnt(16)" ::: "memory");                         \
    __builtin_amdgcn_sched_barrier(0);                                        \
    __builtin_amdgcn_s_barrier();                                             \
    __builtin_amdgcn_sched_barrier(0);                                        \
    const float* rowp = &Abuf[s & 3][0] + (wr * 16 + q) * 128;                \
    _Pragma("unroll")                                                         \
    for (int kk = 0; kk < 4; ++kk) {                                          \
      f32x4 a0 = *(const f32x4*)(rowp + ((kk * 8 + ((2 * g) ^ q7)) << 2));    \
      f32x4 a1 = *(const f32x4*)(rowp + ((kk * 8 + ((2 * g + 1) ^ q7)) << 2));\
      u32x4 wv;                                                               \
      wv[0] = cvtpk(a0[0], a0[1]); wv[1] = cvtpk(a0[2], a0[3]);               \
      wv[2] = cvtpk(a1[0], a1[1]); wv[3] = cvtpk(a1[2], a1[3]);               \
      acc0 = __builtin_amdgcn_mfma_f32_16x16x32_bf16(                         \
          __builtin_bit_cast(s16x8, wv), BR[kk * 2 + 0], acc0, 0, 0, 0);      \
      acc1 = __builtin_amdgcn_mfma_f32_16x16x32_bf16(                         \
          __builtin_bit_cast(s16x8, wv), BR[kk * 2 + 1], acc1, 0, 0, 0);      \
    }                                                                         \
    ++s;                                                                      \
  } while (0)

  for (int it = 0; it < NSTEP / 2; ++it) {
    K2STEP(bB, bA);  // consume B(s)=bA, prefetch B(s+1) into bB
    K2STEP(bA, bB);
  }
#undef K2STEP
#undef GLL4
#undef AADV
#undef LDB

  // drain overrun glls before s_endpgm (LDS may be re-assigned)
  asm volatile("s_waitcnt vmcnt(0)" ::: "memory");

  // epilogue: add self-term, relu, direct store
  const int c = wc * 32 + q;
#pragma unroll
  for (int ct = 0; ct < 2; ++ct) {
    f32x4 av = ct ? acc1 : acc0;
#pragma unroll
    for (int rr = 0; rr < 4; ++rr) {
      int i = i0 + wr * 16 + g * 4 + rr;
      size_t idx = ((size_t)(b * NDIM) + i) * CDIM + c + ct * 16;
      float v = av[rr] + S[idx];
      out[idx] = v > 0.f ? v : 0.f;
    }
  }
}

extern "C" void kernel_launch(void* const* d_in, const int* in_sizes, int n_in,
                              void* d_out, int out_size, void* d_ws, size_t ws_size,
                              hipStream_t stream) {
  const float* V  = (const float*)d_in[0];
  const float* A  = (const float*)d_in[1];
  const float* hw = (const float*)d_in[2];
  float* out = (float*)d_out;

  float* S = (float*)d_ws;
  unsigned short* Ut3 =
      (unsigned short*)((char*)d_ws + (size_t)BDIM * NDIM * CDIM * sizeof(float));

  k1_precompute<<<dim3(NDIM / 16, LDIM + 1, BDIM), 64, 0, stream>>>(V, hw, S, Ut3);
  k2_main<<<dim3((NDIM / 32) * BDIM), 256, 0, stream>>>(A, Ut3, S, out);
}

// Round 8
// 49.549 us; speedup vs baseline: 1.0851x; 1.0851x over previous
//
#include <hip/hip_runtime.h>
#include <cstdint>

#define BDIM 4
#define NDIM 2048
#define FDIM 64
#define CDIM 64
#define LDIM 3
#define KTOT (NDIM * LDIM)   /* 6144 */
#define BK 512
#define NSTEP (KTOT / BK)    /* 12 */
#define KB (KTOT / 32)       /* 192 */

typedef __attribute__((ext_vector_type(4))) float f32x4;
typedef __attribute__((ext_vector_type(8))) short s16x8;
typedef __attribute__((ext_vector_type(4))) unsigned int u32x4;

__device__ __forceinline__ unsigned short f2bf(float x) {
  union { float f; uint32_t u; } v; v.f = x;
  uint32_t r = v.u + 0x7FFFu + ((v.u >> 16) & 1u);
  return (unsigned short)(r >> 16);
}

__device__ __forceinline__ uint32_t cvtpk(float lo, float hi) {
  uint32_t r;
  asm("v_cvt_pk_bf16_f32 %0, %1, %2" : "=v"(r) : "v"(lo), "v"(hi));
  return r;
}

// ---------------------------------------------------------------------------
// K1: S[b,i,c] = sum_f h0[c,f] V[b,i,f]   (fp32, ws)
//     Ut3[b][kb][cw][g][q][e] = U[b][c=cw*16+q][k=kb*32+g*8+e]  (bf16, ws)
//     where U[b][c][k=j*3+l] = sum_f h_{1+l}[c,f] V[b,j,f].
// Layout: k2's per-(kb,cw) wave B-load is 1 KB contiguous (lane*16B).
// MFMA 16x16x32 lane maps (verified R1-R7, absmax 0.5):
//   A: row=l&15, k=(l>>4)*8+e ; B: col=l&15, same k ; D: col=l&15, row=(l>>4)*4+rr
// ---------------------------------------------------------------------------
__global__ __launch_bounds__(64) void k1_precompute(
    const float* __restrict__ V, const float* __restrict__ hw,
    float* __restrict__ S, unsigned short* __restrict__ Ut3) {
  const int j0 = blockIdx.x * 16;
  const int le = blockIdx.y;
  const int b  = blockIdx.z;
  const int lane = threadIdx.x;
  const int q = lane & 15, g = lane >> 4;

  const float* vrow = V + ((size_t)(b * NDIM + j0 + q)) * FDIM + g * 8;
  f32x4 va0 = *(const f32x4*)(vrow);
  f32x4 va1 = *(const f32x4*)(vrow + 4);
  f32x4 va2 = *(const f32x4*)(vrow + 32);
  f32x4 va3 = *(const f32x4*)(vrow + 36);
  s16x8 a0, a1;
#pragma unroll
  for (int e = 0; e < 4; ++e) {
    a0[e]     = (short)f2bf(va0[e]);
    a0[e + 4] = (short)f2bf(va1[e]);
    a1[e]     = (short)f2bf(va2[e]);
    a1[e + 4] = (short)f2bf(va3[e]);
  }

  const float* hbase = hw + (size_t)le * CDIM * FDIM;
#pragma unroll
  for (int ct = 0; ct < 4; ++ct) {
    const float* hrow = hbase + (size_t)(ct * 16 + q) * FDIM + g * 8;
    f32x4 hb0 = *(const f32x4*)(hrow);
    f32x4 hb1 = *(const f32x4*)(hrow + 4);
    f32x4 hb2 = *(const f32x4*)(hrow + 32);
    f32x4 hb3 = *(const f32x4*)(hrow + 36);
    s16x8 b0, b1;
#pragma unroll
    for (int e = 0; e < 4; ++e) {
      b0[e]     = (short)f2bf(hb0[e]);
      b0[e + 4] = (short)f2bf(hb1[e]);
      b1[e]     = (short)f2bf(hb2[e]);
      b1[e + 4] = (short)f2bf(hb3[e]);
    }
    f32x4 acc = {0.f, 0.f, 0.f, 0.f};
    acc = __builtin_amdgcn_mfma_f32_16x16x32_bf16(a0, b0, acc, 0, 0, 0);
    acc = __builtin_amdgcn_mfma_f32_16x16x32_bf16(a1, b1, acc, 0, 0, 0);
    if (le == 0) {
#pragma unroll
      for (int rr = 0; rr < 4; ++rr) {
        int j = j0 + g * 4 + rr;
        S[((size_t)b * NDIM + j) * CDIM + ct * 16 + q] = acc[rr];
      }
    } else {
#pragma unroll
      for (int rr = 0; rr < 4; ++rr) {
        int j = j0 + g * 4 + rr;
        int k = j * 3 + (le - 1);
        int kb = k >> 5, gg = (k >> 3) & 3, ee = k & 7;
        size_t off = ((size_t)b * KB + kb) * 2048 + (size_t)ct * 512 +
                     (size_t)gg * 128 + (size_t)q * 8 + ee;
        Ut3[off] = f2bf(acc[rr]);
      }
    }
  }
}

// ---------------------------------------------------------------------------
// K2: out[b, i0..i0+15, :] = relu(S + A[b,i0:i0+16,:] @ U[b])
// M=16, BK=512/step, 12 steps, grid 512 = 2 blocks/CU, 4 waves (wave w ->
// cols w*16..+15). A contiguity is the lever (R5/R6/R7 monotone): each wave
// stages rows 4w..4w+3 as TWO back-to-back 1KB GLLs per row = 2 KB/stream
// per DRAM page visit. Ring 2 x 32 KB slots (64 KB static LDS).
// Source granules XOR-preswizzled by row&7 (involution; read applies same).
// Two barriers/step (ring-2 requires end-of-step barrier: slot (s+1)&1's
// readers are step s-1, which passed the end barrier before GLL(s+1) issues).
// Counted waits: vmcnt(16) before H0 (newer-than-{A(s),B_H0(s)} =
// GLL(s+1)x8 + B_H1(s)x8); vmcnt(8) before H1 (newer = B_H0(s+1)x8).
// NEVER vmcnt(0) in the loop.
// ---------------------------------------------------------------------------
__global__ __launch_bounds__(256) void k2_main(
    const float* __restrict__ A, const unsigned short* __restrict__ Ut3,
    const float* __restrict__ S, float* __restrict__ out) {
  __shared__ float Abuf[2][8192];  // 2 slots x 16 rows x 512 floats = 64 KB

  const int bid = blockIdx.x;
  const int swz = (bid & 7) * 64 + (bid >> 3);  // XCD-chunked, 512 % 8 == 0
  const int b   = swz >> 7;
  const int i0  = (swz & 127) * 16;
  const int tid = threadIdx.x;
  const int lane = tid & 63, w = tid >> 6;
  const int q = lane & 15, g = lane >> 4, q7 = q & 7;

  // A sources: wave w stages rows 4w..4w+3; per row two 1KB GLLs (p=0,1).
  // Granule swizzle within each 1KB piece: lane ^ (row&7) (involution).
  const float* agp[4];
#pragma unroll
  for (int t = 0; t < 4; ++t) {
    int r = 4 * w + t;
    agp[t] = A + ((size_t)(b * NDIM + i0 + r)) * KTOT + ((lane ^ (r & 7)) * 4);
  }

  // B source: col group cw=w, kb-major; per step 16 kb x 1KB contiguous.
  const unsigned short* bgp =
      Ut3 + (size_t)b * KB * 2048 + (size_t)w * 512 + (size_t)lane * 8;

  // LDS dest: wave's row-block base + lane*16B (linear; GLL requirement)
  float* ldsw = &Abuf[0][0] + w * 4 * 512 + lane * 4;

#define GLL8(slot)                                                            \
  do {                                                                        \
    _Pragma("unroll")                                                         \
    for (int t = 0; t < 4; ++t) {                                             \
      __builtin_amdgcn_global_load_lds(                                       \
          (__attribute__((address_space(1))) void*)(agp[t]),                  \
          (__attribute__((address_space(3))) void*)(ldsw + (slot) * 8192 + t * 512), \
          16, 0, 0);                                                          \
      __builtin_amdgcn_global_load_lds(                                       \
          (__attribute__((address_space(1))) void*)(agp[t] + 256),            \
          (__attribute__((address_space(3))) void*)(ldsw + (slot) * 8192 + t * 512 + 256), \
          16, 0, 0);                                                          \
    }                                                                         \
  } while (0)

#define AADV(cond)                                                            \
  do { if (cond) { agp[0] += BK; agp[1] += BK; agp[2] += BK; agp[3] += BK; } } while (0)

#define LDB(BW, kbase)                                                        \
  do {                                                                        \
    _Pragma("unroll")                                                         \
    for (int t = 0; t < 8; ++t)                                               \
      BW[t] = *(const s16x8*)(bgp + (size_t)((kbase) + t) * 2048);            \
  } while (0)

  f32x4 accA = {0.f, 0.f, 0.f, 0.f}, accB = {0.f, 0.f, 0.f, 0.f};
  s16x8 bA[8], bB[8];

  // prologue: GLL(0)x8, B_H0(0)x8 -> bA
  GLL8(0); AADV(true);
  LDB(bA, 0);

#define HALF(half, BR)                                                        \
  do {                                                                        \
    const float* rowp = &Abuf[s & 1][0] + q * 512;                            \
    _Pragma("unroll")                                                         \
    for (int kk = 0; kk < 8; ++kk) {                                          \
      int kg = (half) * 8 + kk;                                               \
      f32x4 a0 = *(const f32x4*)(rowp + ((kg * 8 + ((2 * g) ^ q7)) << 2));    \
      f32x4 a1 = *(const f32x4*)(rowp + ((kg * 8 + ((2 * g + 1) ^ q7)) << 2));\
      u32x4 wv;                                                               \
      wv[0] = cvtpk(a0[0], a0[1]); wv[1] = cvtpk(a0[2], a0[3]);               \
      wv[2] = cvtpk(a1[0], a1[1]); wv[3] = cvtpk(a1[2], a1[3]);               \
      if (kk & 1)                                                             \
        accB = __builtin_amdgcn_mfma_f32_16x16x32_bf16(                       \
            __builtin_bit_cast(s16x8, wv), BR[kk], accB, 0, 0, 0);            \
      else                                                                    \
        accA = __builtin_amdgcn_mfma_f32_16x16x32_bf16(                       \
            __builtin_bit_cast(s16x8, wv), BR[kk], accA, 0, 0, 0);            \
    }                                                                         \
  } while (0)

  for (int s = 0; s < NSTEP; ++s) {
    GLL8((s + 1) & 1);               // writes other slot; readers passed
    AADV(s + 2 < NSTEP);             //   end-barrier of step s-1 (race-free)
    LDB(bB, 8);                      // B_H1(s): kb 8..15 of this step
    if (s + 1 < NSTEP) bgp += 16 * 2048;  // advance to next step's base
    asm volatile("s_waitcnt vmcnt(16)" ::: "memory");
    __builtin_amdgcn_sched_barrier(0);
    __builtin_amdgcn_s_barrier();    // A(s) visible to all waves
    __builtin_amdgcn_sched_barrier(0);
    HALF(0, bA);                     // kb 0..7 with A(s) lo-half
    LDB(bA, 0);                      // B_H0(s+1) (s=11: re-reads, unused)
    asm volatile("s_waitcnt vmcnt(8)" ::: "memory");
    __builtin_amdgcn_sched_barrier(0);
    HALF(1, bB);                     // kb 8..15
    __builtin_amdgcn_s_barrier();    // end-of-step: protect slot (s+1)&1
  }
#undef HALF
#undef GLL8
#undef AADV
#undef LDB

  // drain overrun glls before s_endpgm (LDS may be re-assigned)
  asm volatile("s_waitcnt vmcnt(0)" ::: "memory");

  // epilogue: add self-term, relu, direct store
  f32x4 acc = accA + accB;
  const int c = w * 16 + q;
#pragma unroll
  for (int rr = 0; rr < 4; ++rr) {
    int i = i0 + g * 4 + rr;
    size_t idx = ((size_t)(b * NDIM) + i) * CDIM + c;
    float v = acc[rr] + S[idx];
    out[idx] = v > 0.f ? v : 0.f;
  }
}

extern "C" void kernel_launch(void* const* d_in, const int* in_sizes, int n_in,
                              void* d_out, int out_size, void* d_ws, size_t ws_size,
                              hipStream_t stream) {
  const float* V  = (const float*)d_in[0];
  const float* A  = (const float*)d_in[1];
  const float* hw = (const float*)d_in[2];
  float* out = (float*)d_out;

  float* S = (float*)d_ws;
  unsigned short* Ut3 =
      (unsigned short*)((char*)d_ws + (size_t)BDIM * NDIM * CDIM * sizeof(float));

  k1_precompute<<<dim3(NDIM / 16, LDIM + 1, BDIM), 64, 0, stream>>>(V, hw, S, Ut3);
  k2_main<<<dim3((NDIM / 16) * BDIM), 256, 0, stream>>>(A, Ut3, S, out);
}

// Round 9
// 49.344 us; speedup vs baseline: 1.0896x; 1.0042x over previous
//
#include <hip/hip_runtime.h>
#include <cstdint>

#define BDIM 4
#define NDIM 2048
#define FDIM 64
#define CDIM 64
#define LDIM 3
#define KTOT (NDIM * LDIM)   /* 6144 */
#define BK 256
#define NSTEP (KTOT / BK)    /* 24 */
#define KB (KTOT / 32)       /* 192 */
#define BSTEP (8 * 2048)     /* B shorts per step */
#define BTOT (KB * 2048)     /* B shorts per batch */

typedef __attribute__((ext_vector_type(4))) float f32x4;
typedef __attribute__((ext_vector_type(8))) short s16x8;
typedef __attribute__((ext_vector_type(4))) unsigned int u32x4;

__device__ __forceinline__ unsigned short f2bf(float x) {
  union { float f; uint32_t u; } v; v.f = x;
  uint32_t r = v.u + 0x7FFFu + ((v.u >> 16) & 1u);
  return (unsigned short)(r >> 16);
}

__device__ __forceinline__ uint32_t cvtpk(float lo, float hi) {
  uint32_t r;
  asm("v_cvt_pk_bf16_f32 %0, %1, %2" : "=v"(r) : "v"(lo), "v"(hi));
  return r;
}

// ---------------------------------------------------------------------------
// K1: S[b,i,c] = sum_f h0[c,f] V[b,i,f]   (fp32, ws)
//     Ut3[b][kb][cw][g][q][e] = U[b][c=cw*16+q][k=kb*32+g*8+e]  (bf16, ws)
//     where U[b][c][k=j*3+l] = sum_f h_{1+l}[c,f] V[b,j,f].
// Layout: k2's per-(kb,cw) wave B-load is 1 KB contiguous (lane*16B).
// MFMA 16x16x32 lane maps (verified R1-R8, absmax 0.5):
//   A: row=l&15, k=(l>>4)*8+e ; B: col=l&15, same k ; D: col=l&15, row=(l>>4)*4+rr
// ---------------------------------------------------------------------------
__global__ __launch_bounds__(64) void k1_precompute(
    const float* __restrict__ V, const float* __restrict__ hw,
    float* __restrict__ S, unsigned short* __restrict__ Ut3) {
  const int j0 = blockIdx.x * 16;
  const int le = blockIdx.y;
  const int b  = blockIdx.z;
  const int lane = threadIdx.x;
  const int q = lane & 15, g = lane >> 4;

  const float* vrow = V + ((size_t)(b * NDIM + j0 + q)) * FDIM + g * 8;
  f32x4 va0 = *(const f32x4*)(vrow);
  f32x4 va1 = *(const f32x4*)(vrow + 4);
  f32x4 va2 = *(const f32x4*)(vrow + 32);
  f32x4 va3 = *(const f32x4*)(vrow + 36);
  s16x8 a0, a1;
#pragma unroll
  for (int e = 0; e < 4; ++e) {
    a0[e]     = (short)f2bf(va0[e]);
    a0[e + 4] = (short)f2bf(va1[e]);
    a1[e]     = (short)f2bf(va2[e]);
    a1[e + 4] = (short)f2bf(va3[e]);
  }

  const float* hbase = hw + (size_t)le * CDIM * FDIM;
#pragma unroll
  for (int ct = 0; ct < 4; ++ct) {
    const float* hrow = hbase + (size_t)(ct * 16 + q) * FDIM + g * 8;
    f32x4 hb0 = *(const f32x4*)(hrow);
    f32x4 hb1 = *(const f32x4*)(hrow + 4);
    f32x4 hb2 = *(const f32x4*)(hrow + 32);
    f32x4 hb3 = *(const f32x4*)(hrow + 36);
    s16x8 b0, b1;
#pragma unroll
    for (int e = 0; e < 4; ++e) {
      b0[e]     = (short)f2bf(hb0[e]);
      b0[e + 4] = (short)f2bf(hb1[e]);
      b1[e]     = (short)f2bf(hb2[e]);
      b1[e + 4] = (short)f2bf(hb3[e]);
    }
    f32x4 acc = {0.f, 0.f, 0.f, 0.f};
    acc = __builtin_amdgcn_mfma_f32_16x16x32_bf16(a0, b0, acc, 0, 0, 0);
    acc = __builtin_amdgcn_mfma_f32_16x16x32_bf16(a1, b1, acc, 0, 0, 0);
    if (le == 0) {
#pragma unroll
      for (int rr = 0; rr < 4; ++rr) {
        int j = j0 + g * 4 + rr;
        S[((size_t)b * NDIM + j) * CDIM + ct * 16 + q] = acc[rr];
      }
    } else {
#pragma unroll
      for (int rr = 0; rr < 4; ++rr) {
        int j = j0 + g * 4 + rr;
        int k = j * 3 + (le - 1);
        int kb = k >> 5, gg = (k >> 3) & 3, ee = k & 7;
        size_t off = ((size_t)b * KB + kb) * 2048 + (size_t)ct * 512 +
                     (size_t)gg * 128 + (size_t)q * 8 + ee;
        Ut3[off] = f2bf(acc[rr]);
      }
    }
  }
}

// ---------------------------------------------------------------------------
// K2: out[b, i0..i0+15, :] = relu(S + A[b,i0:i0+16,:] @ U[b])
// EXACT R6 structure (best: 1KB GLL granules, ring 4x16KB, ahead-2,
// vmcnt(12), one barrier/step, 2 blocks/CU) + ONE change:
// per-block K-PHASE ROTATION s0 = bid % NSTEP with wrap-around offsets.
// Rationale: lockstep k-progression put every block's read at the same
// k-offset simultaneously -> HBM channel-select bits (low addr bits) were
// identical chip-wide -> channel hotspotting capped A-reads at ~4.7 TB/s.
// Rotation spreads instantaneous reads uniformly over all 24 k-windows.
// Accumulation is k-order-independent; tail offsets freeze (re-read L2-hot).
// ---------------------------------------------------------------------------
__global__ __launch_bounds__(256) void k2_main(
    const float* __restrict__ A, const unsigned short* __restrict__ Ut3,
    const float* __restrict__ S, float* __restrict__ out) {
  __shared__ float Abuf[4][4096];  // 4 slots x 16 rows x 256 floats = 64 KB

  const int bid = blockIdx.x;
  const int swz = (bid & 7) * 64 + (bid >> 3);  // XCD-chunked, 512 % 8 == 0
  const int b   = swz >> 7;
  const int i0  = (swz & 127) * 16;
  const int s0  = bid % NSTEP;                  // k-phase rotation
  const int tid = threadIdx.x;
  const int lane = tid & 63, w = tid >> 6;
  const int q = lane & 15, g = lane >> 4, q7 = q & 7;

  // A row bases: wave w stages rows 4w..4w+3, 1 KB contiguous per GLL;
  // 16B granules XOR-preswizzled by row&7 (involution; read applies same).
  const float* agb[4];
#pragma unroll
  for (int t = 0; t < 4; ++t) {
    int r = 4 * w + t;
    agb[t] = A + ((size_t)(b * NDIM + i0 + r)) * KTOT + ((lane ^ (r & 7)) * 4);
  }
  int akoff = s0 * BK;  // k-offset in floats, wraps at KTOT

  // B base: col group cw=w; per step 8 kb x 1KB contiguous
  const unsigned short* bgb =
      Ut3 + (size_t)b * BTOT + (size_t)w * 512 + (size_t)lane * 8;
  int bkoff = s0 * BSTEP;  // offset in shorts, wraps at BTOT

  // LDS dest: wave-uniform base + lane*16B (GLL requirement)
  float* ldsw = &Abuf[0][0] + w * 1024 + lane * 4;

#define GLL4(slot)                                                            \
  do {                                                                        \
    __builtin_amdgcn_global_load_lds(                                         \
        (__attribute__((address_space(1))) void*)(agb[0] + akoff),            \
        (__attribute__((address_space(3))) void*)(ldsw + (slot) * 4096), 16, 0, 0); \
    __builtin_amdgcn_global_load_lds(                                         \
        (__attribute__((address_space(1))) void*)(agb[1] + akoff),            \
        (__attribute__((address_space(3))) void*)(ldsw + (slot) * 4096 + 256), 16, 0, 0); \
    __builtin_amdgcn_global_load_lds(                                         \
        (__attribute__((address_space(1))) void*)(agb[2] + akoff),            \
        (__attribute__((address_space(3))) void*)(ldsw + (slot) * 4096 + 512), 16, 0, 0); \
    __builtin_amdgcn_global_load_lds(                                         \
        (__attribute__((address_space(1))) void*)(agb[3] + akoff),            \
        (__attribute__((address_space(3))) void*)(ldsw + (slot) * 4096 + 768), 16, 0, 0); \
  } while (0)

#define AADV(cond)                                                            \
  do { if (cond) { akoff += BK; if (akoff >= KTOT) akoff = 0; } } while (0)

#define LDB(BW)                                                               \
  do {                                                                        \
    _Pragma("unroll")                                                         \
    for (int t = 0; t < 8; ++t)                                               \
      BW[t] = *(const s16x8*)(bgb + bkoff + (size_t)t * 2048);                \
  } while (0)

#define BADV(cond)                                                            \
  do { if (cond) { bkoff += BSTEP; if (bkoff >= BTOT) bkoff = 0; } } while (0)

  f32x4 accA = {0.f, 0.f, 0.f, 0.f}, accB = {0.f, 0.f, 0.f, 0.f};
  s16x8 bA[8], bB[8];

  // prologue: [A(0)x4, A(1)x4, B(0)x8] = 16 vmem ops (phase-relative steps)
  GLL4(0); AADV(true);
  GLL4(1); AADV(true);
  LDB(bA); BADV(true);

  int s = 0;
  // region s issues {GLL(s+2)x4, B(s+1)x8}; vmcnt(12) => A(s) in LDS, B(s)
  // in regs. GLL(s+2) overwrites slot (s+2)&3, last read at step s-2 whose
  // readers passed barrier s-1 => race-free with one barrier per step.
#define K2STEP(BW, BR)                                                        \
  do {                                                                        \
    GLL4((s + 2) & 3);                                                        \
    AADV(s + 3 < NSTEP); /* else re-read frozen (L2-hot) addrs, unused */     \
    LDB(BW);                                                                  \
    BADV(s + 2 < NSTEP);                                                      \
    asm volatile("s_waitcnt vmcnt(12)" ::: "memory");                         \
    __builtin_amdgcn_sched_barrier(0);                                        \
    __builtin_amdgcn_s_barrier();                                             \
    __builtin_amdgcn_sched_barrier(0);                                        \
    const float* rowp = &Abuf[s & 3][0] + q * 256;                            \
    _Pragma("unroll")                                                         \
    for (int kk = 0; kk < 8; ++kk) {                                          \
      f32x4 a0 = *(const f32x4*)(rowp + ((kk * 8 + ((2 * g) ^ q7)) << 2));    \
      f32x4 a1 = *(const f32x4*)(rowp + ((kk * 8 + ((2 * g + 1) ^ q7)) << 2));\
      u32x4 wv;                                                               \
      wv[0] = cvtpk(a0[0], a0[1]); wv[1] = cvtpk(a0[2], a0[3]);               \
      wv[2] = cvtpk(a1[0], a1[1]); wv[3] = cvtpk(a1[2], a1[3]);               \
      if (kk & 1)                                                             \
        accB = __builtin_amdgcn_mfma_f32_16x16x32_bf16(                       \
            __builtin_bit_cast(s16x8, wv), BR[kk], accB, 0, 0, 0);            \
      else                                                                    \
        accA = __builtin_amdgcn_mfma_f32_16x16x32_bf16(                       \
            __builtin_bit_cast(s16x8, wv), BR[kk], accA, 0, 0, 0);            \
    }                                                                         \
    ++s;                                                                      \
  } while (0)

  for (int it = 0; it < NSTEP / 2; ++it) {
    K2STEP(bB, bA);  // consume B(s)=bA, prefetch B(s+1) into bB
    K2STEP(bA, bB);
  }
#undef K2STEP
#undef GLL4
#undef AADV
#undef LDB
#undef BADV

  // drain overrun glls before s_endpgm (LDS may be re-assigned)
  asm volatile("s_waitcnt vmcnt(0)" ::: "memory");

  // epilogue: add self-term, relu, direct store
  f32x4 acc = accA + accB;
  const int c = w * 16 + q;
#pragma unroll
  for (int rr = 0; rr < 4; ++rr) {
    int i = i0 + g * 4 + rr;
    size_t idx = ((size_t)(b * NDIM) + i) * CDIM + c;
    float v = acc[rr] + S[idx];
    out[idx] = v > 0.f ? v : 0.f;
  }
}

extern "C" void kernel_launch(void* const* d_in, const int* in_sizes, int n_in,
                              void* d_out, int out_size, void* d_ws, size_t ws_size,
                              hipStream_t stream) {
  const float* V  = (const float*)d_in[0];
  const float* A  = (const float*)d_in[1];
  const float* hw = (const float*)d_in[2];
  float* out = (float*)d_out;

  float* S = (float*)d_ws;
  unsigned short* Ut3 =
      (unsigned short*)((char*)d_ws + (size_t)BDIM * NDIM * CDIM * sizeof(float));

  k1_precompute<<<dim3(NDIM / 16, LDIM + 1, BDIM), 64, 0, stream>>>(V, hw, S, Ut3);
  k2_main<<<dim3((NDIM / 16) * BDIM), 256, 0, stream>>>(A, Ut3, S, out);
}

// Round 10
// 46.518 us; speedup vs baseline: 1.1558x; 1.0607x over previous
//
#include <hip/hip_runtime.h>
#include <cstdint>

#define BDIM 4
#define NDIM 2048
#define FDIM 64
#define CDIM 64
#define LDIM 3
#define KTOT (NDIM * LDIM)   /* 6144 */
#define BK 256
#define NSTEP (KTOT / BK)    /* 24 */
#define KB (KTOT / 32)       /* 192 */
#define BSTEP (8 * 2048)     /* B shorts per step */
#define BTOT (KB * 2048)     /* B shorts per batch */

typedef __attribute__((ext_vector_type(4))) float f32x4;
typedef __attribute__((ext_vector_type(8))) short s16x8;
typedef __attribute__((ext_vector_type(4))) unsigned int u32x4;

__device__ __forceinline__ unsigned short f2bf(float x) {
  union { float f; uint32_t u; } v; v.f = x;
  uint32_t r = v.u + 0x7FFFu + ((v.u >> 16) & 1u);
  return (unsigned short)(r >> 16);
}

__device__ __forceinline__ uint32_t cvtpk(float lo, float hi) {
  uint32_t r;
  asm("v_cvt_pk_bf16_f32 %0, %1, %2" : "=v"(r) : "v"(lo), "v"(hi));
  return r;
}

// ---------------------------------------------------------------------------
// K1: S[b,i,c] = sum_f h0[c,f] V[b,i,f]   (fp32, ws)
//     Ut3[b][kb][cw][g][q][e] = U[b][c=cw*16+q][k=kb*32+g*8+e]  (bf16, ws)
//     where U[b][c][k=j*3+l] = sum_f h_{1+l}[c,f] V[b,j,f].
// Layout: k2's per-(kb,cw) wave B-load is 1 KB contiguous (lane*16B).
// MFMA 16x16x32 lane maps (verified R1-R9, absmax 0.5):
//   A: row=l&15, k=(l>>4)*8+e ; B: col=l&15, same k ; D: col=l&15, row=(l>>4)*4+rr
// ---------------------------------------------------------------------------
__global__ __launch_bounds__(64) void k1_precompute(
    const float* __restrict__ V, const float* __restrict__ hw,
    float* __restrict__ S, unsigned short* __restrict__ Ut3) {
  const int j0 = blockIdx.x * 16;
  const int le = blockIdx.y;
  const int b  = blockIdx.z;
  const int lane = threadIdx.x;
  const int q = lane & 15, g = lane >> 4;

  const float* vrow = V + ((size_t)(b * NDIM + j0 + q)) * FDIM + g * 8;
  f32x4 va0 = *(const f32x4*)(vrow);
  f32x4 va1 = *(const f32x4*)(vrow + 4);
  f32x4 va2 = *(const f32x4*)(vrow + 32);
  f32x4 va3 = *(const f32x4*)(vrow + 36);
  s16x8 a0, a1;
#pragma unroll
  for (int e = 0; e < 4; ++e) {
    a0[e]     = (short)f2bf(va0[e]);
    a0[e + 4] = (short)f2bf(va1[e]);
    a1[e]     = (short)f2bf(va2[e]);
    a1[e + 4] = (short)f2bf(va3[e]);
  }

  const float* hbase = hw + (size_t)le * CDIM * FDIM;
#pragma unroll
  for (int ct = 0; ct < 4; ++ct) {
    const float* hrow = hbase + (size_t)(ct * 16 + q) * FDIM + g * 8;
    f32x4 hb0 = *(const f32x4*)(hrow);
    f32x4 hb1 = *(const f32x4*)(hrow + 4);
    f32x4 hb2 = *(const f32x4*)(hrow + 32);
    f32x4 hb3 = *(const f32x4*)(hrow + 36);
    s16x8 b0, b1;
#pragma unroll
    for (int e = 0; e < 4; ++e) {
      b0[e]     = (short)f2bf(hb0[e]);
      b0[e + 4] = (short)f2bf(hb1[e]);
      b1[e]     = (short)f2bf(hb2[e]);
      b1[e + 4] = (short)f2bf(hb3[e]);
    }
    f32x4 acc = {0.f, 0.f, 0.f, 0.f};
    acc = __builtin_amdgcn_mfma_f32_16x16x32_bf16(a0, b0, acc, 0, 0, 0);
    acc = __builtin_amdgcn_mfma_f32_16x16x32_bf16(a1, b1, acc, 0, 0, 0);
    if (le == 0) {
#pragma unroll
      for (int rr = 0; rr < 4; ++rr) {
        int j = j0 + g * 4 + rr;
        S[((size_t)b * NDIM + j) * CDIM + ct * 16 + q] = acc[rr];
      }
    } else {
#pragma unroll
      for (int rr = 0; rr < 4; ++rr) {
        int j = j0 + g * 4 + rr;
        int k = j * 3 + (le - 1);
        int kb = k >> 5, gg = (k >> 3) & 3, ee = k & 7;
        size_t off = ((size_t)b * KB + kb) * 2048 + (size_t)ct * 512 +
                     (size_t)gg * 128 + (size_t)q * 8 + ee;
        Ut3[off] = f2bf(acc[rr]);
      }
    }
  }
}

// ---------------------------------------------------------------------------
// K2: out[b, i0..i0+31, :] = relu(S + A[b,i0:i0+32,:] @ U[b])
// M=32, 512 threads (8 waves), BK=256/step, 24 steps, grid 256 = 1 block/CU.
// Theory: per-CU L1 return-path ceiling ~55 B/cy. R6 demanded 74 B/cy
// (A 32KB + B 64KB per 1330cy step); here A 32KB + B 32KB = 48 B/cy < cap.
// Wave (wr,wc)=(w>>2,w&3): rows wr*16..+15, cols wc*16..+15; wr-paired
// waves load identical B lines barrier-synced -> L1 dedup.
// A: 1 KB GLL granules (the R6 lever, kept), wave w stages rows 4w..4w+3;
//    16B granules XOR-preswizzled by row&7 (involution; read applies same).
// Ring 2 x 32 KB slots (64 KB static), GLL ahead-1, 2 barriers/step.
// Counted waits, both vmcnt(8) (12 vmem ops/step = 4 GLL + 8 B):
//   pos3: outstanding {GLL(s)4, H0(s)4, H1(s)4, GLL(s+1)4} keep 8 newest
//         -> A(s)+B_H0(s) retired;
//   pos7: outstanding {H1(s)4, GLL(s+1)4, H0(s+1)4} keep 8 newest
//         -> B_H1(s) retired, GLL(s+1) stays in flight.
// NEVER vmcnt(0) in the loop.
// ---------------------------------------------------------------------------
__global__ __launch_bounds__(512) void k2_main(
    const float* __restrict__ A, const unsigned short* __restrict__ Ut3,
    const float* __restrict__ S, float* __restrict__ out) {
  __shared__ float Abuf[2][8192];  // 2 slots x 32 rows x 256 floats = 64 KB

  const int bid = blockIdx.x;
  const int swz = (bid & 7) * 32 + (bid >> 3);  // XCD-chunked, 256 % 8 == 0
  const int b   = swz >> 6;
  const int i0  = (swz & 63) * 32;
  const int tid = threadIdx.x;
  const int lane = tid & 63, w = tid >> 6;
  const int q = lane & 15, g = lane >> 4, q7 = q & 7;
  const int wr = w >> 2, wc = w & 3;

  // A row bases: wave w stages rows 4w..4w+3, 1 KB contiguous per GLL;
  // 16B granules XOR-preswizzled by row&7 (involution; read applies same).
  const float* agb[4];
#pragma unroll
  for (int t = 0; t < 4; ++t) {
    int r = 4 * w + t;
    agb[t] = A + ((size_t)(b * NDIM + i0 + r)) * KTOT + ((lane ^ (r & 7)) * 4);
  }
  int akoff = 0;  // k-offset in floats

  // B base: col group cw=wc; per step 8 kb x 1KB contiguous
  const unsigned short* bgb =
      Ut3 + (size_t)b * BTOT + (size_t)wc * 512 + (size_t)lane * 8;
  int bkoff = 0;  // offset in shorts

  // LDS dest: wave-uniform base + lane*16B (GLL requirement); wave w's
  // rows 4w..4w+3 occupy floats w*1024 .. w*1024+1023 of a slot.
  float* ldsw = &Abuf[0][0] + w * 1024 + lane * 4;

#define GLL4(slot)                                                            \
  do {                                                                        \
    __builtin_amdgcn_global_load_lds(                                         \
        (__attribute__((address_space(1))) void*)(agb[0] + akoff),            \
        (__attribute__((address_space(3))) void*)(ldsw + (slot) * 8192), 16, 0, 0); \
    __builtin_amdgcn_global_load_lds(                                         \
        (__attribute__((address_space(1))) void*)(agb[1] + akoff),            \
        (__attribute__((address_space(3))) void*)(ldsw + (slot) * 8192 + 256), 16, 0, 0); \
    __builtin_amdgcn_global_load_lds(                                         \
        (__attribute__((address_space(1))) void*)(agb[2] + akoff),            \
        (__attribute__((address_space(3))) void*)(ldsw + (slot) * 8192 + 512), 16, 0, 0); \
    __builtin_amdgcn_global_load_lds(                                         \
        (__attribute__((address_space(1))) void*)(agb[3] + akoff),            \
        (__attribute__((address_space(3))) void*)(ldsw + (slot) * 8192 + 768), 16, 0, 0); \
  } while (0)

#define LDB(BW, HB)                                                           \
  do {                                                                        \
    _Pragma("unroll")                                                         \
    for (int t = 0; t < 4; ++t)                                               \
      BW[t] = *(const s16x8*)(bgb + bkoff + (size_t)((HB) + t) * 2048);       \
  } while (0)

#define HALF(half, BR)                                                        \
  do {                                                                        \
    const float* rowp = &Abuf[s & 1][0] + (wr * 16 + q) * 256;                \
    _Pragma("unroll")                                                         \
    for (int kk = 0; kk < 4; ++kk) {                                          \
      int kg = (half) * 4 + kk;                                               \
      f32x4 a0 = *(const f32x4*)(rowp + ((kg * 8 + ((2 * g) ^ q7)) << 2));    \
      f32x4 a1 = *(const f32x4*)(rowp + ((kg * 8 + ((2 * g + 1) ^ q7)) << 2));\
      u32x4 wv;                                                               \
      wv[0] = cvtpk(a0[0], a0[1]); wv[1] = cvtpk(a0[2], a0[3]);               \
      wv[2] = cvtpk(a1[0], a1[1]); wv[3] = cvtpk(a1[2], a1[3]);               \
      if (kk & 1)                                                             \
        accB = __builtin_amdgcn_mfma_f32_16x16x32_bf16(                       \
            __builtin_bit_cast(s16x8, wv), BR[kk], accB, 0, 0, 0);            \
      else                                                                    \
        accA = __builtin_amdgcn_mfma_f32_16x16x32_bf16(                       \
            __builtin_bit_cast(s16x8, wv), BR[kk], accA, 0, 0, 0);            \
    }                                                                         \
  } while (0)

  f32x4 accA = {0.f, 0.f, 0.f, 0.f}, accB = {0.f, 0.f, 0.f, 0.f};
  s16x8 bA[4], bB[4];

  // prologue: GLL(0)x4, B_H0(0)x4 -> bA; akoff advances to step 1
  GLL4(0); akoff = BK;
  LDB(bA, 0);

  for (int s = 0; s < NSTEP; ++s) {
    LDB(bB, 4);                           // B_H1(s) at current bkoff
    GLL4((s + 1) & 1);                    // A(s+1) -> other slot (its readers
                                          //   passed end-barrier of s-1)
    if (s + 2 < NSTEP) akoff += BK;       // tail: re-read last window (dead)
    if (s + 1 < NSTEP) bkoff += BSTEP;    // -> step s+1's B base
    asm volatile("s_waitcnt vmcnt(8)" ::: "memory");  // A(s), B_H0(s) done
    __builtin_amdgcn_sched_barrier(0);
    __builtin_amdgcn_s_barrier();         // A(s) visible to all waves
    __builtin_amdgcn_sched_barrier(0);
    HALF(0, bA);                          // kb 0..3
    LDB(bA, 0);                           // B_H0(s+1) (s=23: re-read, unused)
    asm volatile("s_waitcnt vmcnt(8)" ::: "memory");  // B_H1(s) done;
    __builtin_amdgcn_sched_barrier(0);                // GLL(s+1) stays queued
    HALF(1, bB);                          // kb 4..7
    __builtin_amdgcn_s_barrier();         // end-of-step: protect slot (s+1)&1
  }
#undef HALF
#undef GLL4
#undef LDB

  // drain overrun glls before s_endpgm (LDS may be re-assigned)
  asm volatile("s_waitcnt vmcnt(0)" ::: "memory");

  // epilogue: add self-term, relu, direct store
  f32x4 acc = accA + accB;
  const int c = wc * 16 + q;
#pragma unroll
  for (int rr = 0; rr < 4; ++rr) {
    int i = i0 + wr * 16 + g * 4 + rr;
    size_t idx = ((size_t)(b * NDIM) + i) * CDIM + c;
    float v = acc[rr] + S[idx];
    out[idx] = v > 0.f ? v : 0.f;
  }
}

extern "C" void kernel_launch(void* const* d_in, const int* in_sizes, int n_in,
                              void* d_out, int out_size, void* d_ws, size_t ws_size,
                              hipStream_t stream) {
  const float* V  = (const float*)d_in[0];
  const float* A  = (const float*)d_in[1];
  const float* hw = (const float*)d_in[2];
  float* out = (float*)d_out;

  float* S = (float*)d_ws;
  unsigned short* Ut3 =
      (unsigned short*)((char*)d_ws + (size_t)BDIM * NDIM * CDIM * sizeof(float));

  k1_precompute<<<dim3(NDIM / 16, LDIM + 1, BDIM), 64, 0, stream>>>(V, hw, S, Ut3);
  k2_main<<<dim3((NDIM / 32) * BDIM), 512, 0, stream>>>(A, Ut3, S, out);
}